// Round 9
// baseline (234.521 us; speedup 1.0000x reference)
//
#include <hip/hip_runtime.h>
#include <math.h>

#define NROWS 8192
#define DIMX  1024
#define DKV   128
#define KSPLIT 4
#define KEYS_PER_SPLIT (NROWS / KSPLIT)  // 2048
#define BN 64
// sqrt(log2(e)) -- folded into Wqk/bqk so scores come out in base-2 units
#define QK_SCALE 1.2011224087864498f
// fixed softmax max (base-2 units); see round-6 derivation
#define M_FIX 96.0f

typedef __attribute__((ext_vector_type(8))) short bf16x8;
typedef __attribute__((ext_vector_type(4))) short s16x4;
typedef __attribute__((ext_vector_type(4))) float f32x4;

static __device__ __forceinline__ short f2bf(float f) {
    union { float f; unsigned u; } v; v.f = f;
    unsigned r = v.u + 0x7fff + ((v.u >> 16) & 1);  // RNE
    return (short)(r >> 16);
}

// ---------------------------------------------------------------------------
// wcvt: one-time W/bias convert to bf16 (Wqk,bqk pre-scaled by sqrt(log2 e)).
// ---------------------------------------------------------------------------
__global__ __launch_bounds__(256) void wcvt_kernel(
    const float* __restrict__ Wqk, const float* __restrict__ bqk,
    const float* __restrict__ Wv,  const float* __restrict__ bv,
    short* __restrict__ wb, float* __restrict__ bb)
{
    const int idx = blockIdx.x * 1024 + threadIdx.x * 4;   // 256 blocks x 1024
    const bool isqk = idx < DKV * DIMX;
    const float* src = isqk ? (Wqk + idx) : (Wv + (idx - DKV * DIMX));
    const float sc = isqk ? QK_SCALE : 1.0f;
    const float4 f = *(const float4*)src;
    s16x4 o;
    o.x = f2bf(f.x * sc); o.y = f2bf(f.y * sc);
    o.z = f2bf(f.z * sc); o.w = f2bf(f.w * sc);
    *(s16x4*)&wb[idx] = o;
    if (blockIdx.x == 0) {
        const int t = threadIdx.x;
        bb[t] = (t < DKV) ? bqk[t] * QK_SCALE : bv[t - DKV];
    }
}

// ---------------------------------------------------------------------------
// proj v2: stage-once, zero inner barriers (unchanged, verified).
// ---------------------------------------------------------------------------
__global__ __launch_bounds__(256) void proj_kernel(
    const float* __restrict__ x, const short* __restrict__ wb,
    const float* __restrict__ bb, short* __restrict__ qkb, short* __restrict__ vtb)
{
    __shared__ __align__(16) short xb[32 * 1024];  // 64 KB, XOR-swizzled

    const int tid  = threadIdx.x;
    const int lane = tid & 63;
    const int wave = tid >> 6;
    const int l15  = lane & 15;
    const int quad = lane >> 4;
    const int mat  = blockIdx.y;
    const int rbase = blockIdx.x * 32;
    const int wr = wave >> 1, wc = wave & 1;       // wave: 16 rows x 64 cols
    const short* wsrc = wb + (size_t)mat * DKV * DIMX;

    #pragma unroll 8
    for (int i = 0; i < 32; ++i) {
        const float4 f = *(const float4*)(x + (size_t)(rbase + i) * DIMX + tid * 4);
        s16x4 o;
        o.x = f2bf(f.x); o.y = f2bf(f.y); o.z = f2bf(f.z); o.w = f2bf(f.w);
        *(s16x4*)&xb[i * 1024 + ((tid * 4) ^ ((i & 7) << 3))] = o;
    }
    __syncthreads();

    f32x4 acc[4];
    for (int i = 0; i < 4; ++i) acc[i] = (f32x4)0.0f;

    const int arow = wr * 16 + l15;
    const int aswz = (arow & 7) << 3;
    const short* arowp = &xb[arow * 1024];

    #pragma unroll 2
    for (int kk = 0; kk < 32; ++kk) {              // k0 = kk*32
        const bf16x8 a = *(const bf16x8*)&arowp[(kk * 32 + quad * 8) ^ aswz];
        for (int nt = 0; nt < 4; ++nt) {
            const int col = wc * 64 + nt * 16 + l15;
            const bf16x8 b = *(const bf16x8*)(wsrc + (size_t)col * DIMX + kk * 32 + quad * 8);
            acc[nt] = __builtin_amdgcn_mfma_f32_16x16x32_bf16(a, b, acc[nt], 0, 0, 0);
        }
    }

    const int rw = rbase + wr * 16 + quad * 4;
    for (int nt = 0; nt < 4; ++nt) {
        const int col = wc * 64 + nt * 16 + l15;
        const float bias = bb[mat * DKV + col];
        if (mat == 0) {
            for (int r = 0; r < 4; ++r)
                qkb[(size_t)(rw + r) * DKV + col] = f2bf(acc[nt][r] + bias);
        } else {
            s16x4 o;
            o.x = f2bf(acc[nt][0] + bias); o.y = f2bf(acc[nt][1] + bias);
            o.z = f2bf(acc[nt][2] + bias); o.w = f2bf(acc[nt][3] + bias);
            *(s16x4*)&vtb[(size_t)col * NROWS + rw] = o;
        }
    }
}

// ---------------------------------------------------------------------------
// flash v7: direct-from-L2 K/V, BARRIER-FREE inner loop.
// qkb (2 MB) + vtb (2 MB) fit one XCD's L2 -> staging them through LDS was
// pure overhead (r8 audit: kt/vt reads = ~50% busy on the per-CU LDS pipe,
// the top pipe). K/V fragments now load per-lane from global (byte-identical
// per-lane data to the staged reads -> identical math). No DMA, no kt/vt
// LDS, no per-tile __syncthreads: the 4 waves run fully decoupled and hide
// each other's latency. K-frags double-buffered in registers (ping-pong,
// 2x-unrolled loop, static indices); V-frags load at iter top under the
// QK^T+softmax shadow. LDS = P (wave-private) + merge buffer = 33 KB.
// Fixed-max base-2 softmax, packed P path, lsum-via-MFMA: unchanged (r8).
// ---------------------------------------------------------------------------
__global__ __launch_bounds__(256, 2) void flash_kernel(
    const short* __restrict__ qkb, const short* __restrict__ vtb,
    float* __restrict__ opart, float* __restrict__ lpart)
{
    // smem: [0,16K) per-wave P (4 KB each); after final barrier the first
    // 32 KB is the rg merge buffer, last 256 B the l merge buffer.
    __shared__ __align__(16) char smem[33024];

    const int tid  = threadIdx.x;
    const int lane = tid & 63;
    const int wave = tid >> 6;
    const int l15  = lane & 15;
    const int quad = lane >> 4;
    const int rg   = wave >> 1;                      // row-group (32 rows)
    const int kh   = wave & 1;                       // key-half (32 keys)
    const int rbase = blockIdx.x * 64 + rg * 32;
    const int ks = blockIdx.y;

    short* pw = (short*)(smem + wave * 4096);        // 32 rows x 128 B

    // Q fragments for 32 rows: A[m=lane&15][k=quad*8+j], halves h=0,1
    bf16x8 qf[2][4];
    #pragma unroll 2
    for (int h = 0; h < 2; ++h) {
        const short* qrow = qkb + (size_t)(rbase + h * 16 + l15) * DKV;
        for (int k = 0; k < 4; ++k)
            qf[h][k] = *(const bf16x8*)(qrow + k * 32 + quad * 8);
    }

    // ones-vector (bf16 1.0) for the l-sum MFMA
    bf16x8 ones;
    for (int j = 0; j < 8; ++j) ones[j] = (short)0x3F80;

    f32x4 oacc[2][8];
    #pragma unroll 2
    for (int h = 0; h < 2; ++h)
        for (int i = 0; i < 8; ++i) oacc[h][i] = (f32x4)0.0f;
    f32x4 lsum[2] = {(f32x4)0.0f, (f32x4)0.0f};

    // direct-load base pointers (per-lane)
    // K (interleaved keys): row = j0 + kh*32 + 2*l15 + ntl, 16B chunk quad
    const short* kp0 = qkb + (size_t)(kh * 32 + 2 * l15) * DKV + quad * 8;
    const short* kp1 = kp0 + DKV;
    // V^T: row = d-index nt*16+l15, key offset j0 + kh*32 + quad*8
    const short* vp[8];
    for (int nt = 0; nt < 8; ++nt)
        vp[nt] = vtb + (size_t)(nt * 16 + l15) * NROWS + kh * 32 + quad * 8;

    // P-store/load XOR (bytes): X(row) = ((row>>2)&1)<<6 (r8-verified)
    const int pxw = (quad & 1) << 6;                 // write: row=h*16+quad*4+r
    const int pxr = (l15 & 4) << 4;                  // read:  row=h*16+l15

#define LOADK(dst, j0) do { \
        for (int k_ = 0; k_ < 4; ++k_) { \
            dst[0][k_] = *(const bf16x8*)(kp0 + (size_t)(j0) * DKV + k_ * 32); \
            dst[1][k_] = *(const bf16x8*)(kp1 + (size_t)(j0) * DKV + k_ * 32); \
        } } while (0)

#define TILE(KC, KN, j0, more) do { \
        bf16x8 vf[8]; \
        for (int nt = 0; nt < 8; ++nt) \
            vf[nt] = *(const bf16x8*)(vp[nt] + (j0)); \
        f32x4 s[2][2]; \
        __builtin_amdgcn_s_setprio(1); \
        for (int ntl = 0; ntl < 2; ++ntl) { \
            f32x4 a0 = (f32x4)0.0f, a1 = (f32x4)0.0f; \
            for (int k_ = 0; k_ < 4; ++k_) { \
                a0 = __builtin_amdgcn_mfma_f32_16x16x32_bf16(qf[0][k_], KC[ntl][k_], a0, 0, 0, 0); \
                a1 = __builtin_amdgcn_mfma_f32_16x16x32_bf16(qf[1][k_], KC[ntl][k_], a1, 0, 0, 0); \
            } \
            s[0][ntl] = a0; s[1][ntl] = a1; \
        } \
        __builtin_amdgcn_s_setprio(0); \
        for (int h = 0; h < 2; ++h) \
            for (int ntl = 0; ntl < 2; ++ntl) \
                for (int r = 0; r < 4; ++r) \
                    s[h][ntl][r] = __builtin_amdgcn_exp2f(s[h][ntl][r] - M_FIX); \
        for (int h = 0; h < 2; ++h) \
            for (int r = 0; r < 4; ++r) { \
                const int row = h * 16 + quad * 4 + r; \
                unsigned pk; \
                asm("v_cvt_pk_bf16_f32 %0, %1, %2" : "=v"(pk) : "v"(s[h][0][r]), "v"(s[h][1][r])); \
                *(unsigned*)(pw ? (char*)pw + row * 128 + ((l15 * 4) ^ pxw) : 0) = pk; \
            } \
        if (more) LOADK(KN, (j0) + BN); \
        __builtin_amdgcn_s_setprio(1); \
        { \
            const bf16x8 a0 = *(const bf16x8*)((char*)pw + l15 * 128 + ((quad * 16) ^ pxr)); \
            const bf16x8 a1 = *(const bf16x8*)((char*)pw + (16 + l15) * 128 + ((quad * 16) ^ pxr)); \
            lsum[0] = __builtin_amdgcn_mfma_f32_16x16x32_bf16(a0, ones, lsum[0], 0, 0, 0); \
            lsum[1] = __builtin_amdgcn_mfma_f32_16x16x32_bf16(a1, ones, lsum[1], 0, 0, 0); \
            for (int nt = 0; nt < 8; ++nt) { \
                oacc[0][nt] = __builtin_amdgcn_mfma_f32_16x16x32_bf16(a0, vf[nt], oacc[0][nt], 0, 0, 0); \
                oacc[1][nt] = __builtin_amdgcn_mfma_f32_16x16x32_bf16(a1, vf[nt], oacc[1][nt], 0, 0, 0); \
            } \
        } \
        __builtin_amdgcn_s_setprio(0); \
    } while (0)

    const int j_begin = ks * KEYS_PER_SPLIT;
    const int j_end   = j_begin + KEYS_PER_SPLIT;

    bf16x8 kfA[2][4], kfB[2][4];
    LOADK(kfA, j_begin);
    for (int j0 = j_begin; j0 < j_end; j0 += 2 * BN) {
        TILE(kfA, kfB, j0, true);
        TILE(kfB, kfA, j0 + BN, (j0 + 2 * BN) < j_end);
    }

    // ---- merge the two key-half waves of each row-group (plain adds) ----
    float* obuf = (float*)smem + rg * 32 * 128;      // 32 rows x 128 d fp32
    float* lbuf = (float*)(smem + 32768);            // 64 floats
    __syncthreads();                                 // all waves done with pw
    if (kh == 1) {
        #pragma unroll 2
        for (int h = 0; h < 2; ++h) {
            for (int nt = 0; nt < 8; ++nt)
                for (int r = 0; r < 4; ++r)
                    obuf[(h * 16 + quad * 4 + r) * 128 + nt * 16 + l15] = oacc[h][nt][r];
            if (l15 == 0)
                for (int r = 0; r < 4; ++r)
                    lbuf[rg * 32 + h * 16 + quad * 4 + r] = lsum[h][r];
        }
    }
    __syncthreads();
    if (kh == 0) {
        #pragma unroll 2
        for (int h = 0; h < 2; ++h) {
            const int rw = rbase + h * 16 + quad * 4;
            for (int nt = 0; nt < 8; ++nt) {
                const int col = nt * 16 + l15;
                for (int r = 0; r < 4; ++r)
                    opart[((size_t)ks * NROWS + rw + r) * DKV + col] =
                        oacc[h][nt][r] + obuf[(h * 16 + quad * 4 + r) * 128 + col];
            }
            if (l15 == 0)
                for (int r = 0; r < 4; ++r)
                    lpart[ks * NROWS + rw + r] =
                        lsum[h][r] + lbuf[rg * 32 + h * 16 + quad * 4 + r];
        }
    }
#undef LOADK
#undef TILE
}

// ---------------------------------------------------------------------------
// combine: fixed common max -> plain sums, one divide
// ---------------------------------------------------------------------------
__global__ __launch_bounds__(256) void combine_kernel(
    const float* __restrict__ opart, const float* __restrict__ lpart,
    float* __restrict__ out)
{
    const int idx = blockIdx.x * 256 + threadIdx.x;  // 0 .. N*128-1
    const int row = idx >> 7;
    float L = 0.f, acc = 0.f;
    for (int s = 0; s < KSPLIT; ++s) {
        L   += lpart[s * NROWS + row];
        acc += opart[(size_t)s * NROWS * DKV + idx];
    }
    out[idx] = acc / L;
}

// ---------------------------------------------------------------------------
extern "C" void kernel_launch(void* const* d_in, const int* in_sizes, int n_in,
                              void* d_out, int out_size, void* d_ws, size_t ws_size,
                              hipStream_t stream) {
    const float* x   = (const float*)d_in[0];
    const float* Wqk = (const float*)d_in[1];
    const float* bqk = (const float*)d_in[2];
    const float* Wv  = (const float*)d_in[3];
    const float* bv  = (const float*)d_in[4];
    float* out = (float*)d_out;

    char* ws = (char*)d_ws;
    short* qkb   = (short*)ws;                                   // 2 MB bf16 [N][128]
    short* vtb   = (short*)(ws + (2u << 20));                    // 2 MB bf16 [128][N]
    short* wb    = (short*)(ws + (4u << 20));                    // 512 KB bf16 [2][128][1024]
    float* bb    = (float*)(ws + (4u << 20) + (512u << 10));     // 1 KB fp32 [256]
    float* opart = (float*)(ws + (5u << 20));                    // 16 MB fp32 [KS][N][128]
    float* lpart = (float*)(ws + (21u << 20));                   // 128 KB

    wcvt_kernel<<<dim3(256), 256, 0, stream>>>(Wqk, bqk, Wv, bv, wb, bb);
    proj_kernel<<<dim3(256, 2), 256, 0, stream>>>(x, wb, bb, qkb, vtb);
    flash_kernel<<<dim3(NROWS / 64, KSPLIT), 256, 0, stream>>>(qkb, vtb, opart, lpart);
    combine_kernel<<<dim3(NROWS * DKV / 256), 256, 0, stream>>>(opart, lpart, out);
}

// Round 10
// 190.965 us; speedup vs baseline: 1.2281x; 1.2281x over previous
//
#include <hip/hip_runtime.h>
#include <math.h>

#define NROWS 8192
#define DIMX  1024
#define DKV   128
#define KSPLIT 4
#define KEYS_PER_SPLIT (NROWS / KSPLIT)  // 2048
#define BN 64
// sqrt(log2(e)) -- folded into Wqk/bqk so scores come out in base-2 units
#define QK_SCALE 1.2011224087864498f
// fixed softmax max (base-2 units); see round-6 derivation
#define M_FIX 96.0f

typedef __attribute__((ext_vector_type(8))) short bf16x8;
typedef __attribute__((ext_vector_type(4))) short s16x4;
typedef __attribute__((ext_vector_type(4))) float f32x4;

static __device__ __forceinline__ short f2bf(float f) {
    union { float f; unsigned u; } v; v.f = f;
    unsigned r = v.u + 0x7fff + ((v.u >> 16) & 1);  // RNE
    return (short)(r >> 16);
}

// ---------------------------------------------------------------------------
// wcvt: one-time W/bias convert to bf16 (Wqk,bqk pre-scaled by sqrt(log2 e)).
// ---------------------------------------------------------------------------
__global__ __launch_bounds__(256) void wcvt_kernel(
    const float* __restrict__ Wqk, const float* __restrict__ bqk,
    const float* __restrict__ Wv,  const float* __restrict__ bv,
    short* __restrict__ wb, float* __restrict__ bb)
{
    const int idx = blockIdx.x * 1024 + threadIdx.x * 4;   // 256 blocks x 1024
    const bool isqk = idx < DKV * DIMX;
    const float* src = isqk ? (Wqk + idx) : (Wv + (idx - DKV * DIMX));
    const float sc = isqk ? QK_SCALE : 1.0f;
    const float4 f = *(const float4*)src;
    s16x4 o;
    o.x = f2bf(f.x * sc); o.y = f2bf(f.y * sc);
    o.z = f2bf(f.z * sc); o.w = f2bf(f.w * sc);
    *(s16x4*)&wb[idx] = o;
    if (blockIdx.x == 0) {
        const int t = threadIdx.x;
        bb[t] = (t < DKV) ? bqk[t] * QK_SCALE : bv[t - DKV];
    }
}

// ---------------------------------------------------------------------------
// proj v3 = v2 + software-pipelined B loads (issue kk+1's weight fragments
// before kk's MFMAs -> L2 latency hidden; MFMA chain never waits).
// ---------------------------------------------------------------------------
__global__ __launch_bounds__(256) void proj_kernel(
    const float* __restrict__ x, const short* __restrict__ wb,
    const float* __restrict__ bb, short* __restrict__ qkb, short* __restrict__ vtb)
{
    __shared__ __align__(16) short xb[32 * 1024];  // 64 KB, XOR-swizzled

    const int tid  = threadIdx.x;
    const int lane = tid & 63;
    const int wave = tid >> 6;
    const int l15  = lane & 15;
    const int quad = lane >> 4;
    const int mat  = blockIdx.y;
    const int rbase = blockIdx.x * 32;
    const int wr = wave >> 1, wc = wave & 1;       // wave: 16 rows x 64 cols
    const short* wsrc = wb + (size_t)mat * DKV * DIMX;

    #pragma unroll 8
    for (int i = 0; i < 32; ++i) {
        const float4 f = *(const float4*)(x + (size_t)(rbase + i) * DIMX + tid * 4);
        s16x4 o;
        o.x = f2bf(f.x); o.y = f2bf(f.y); o.z = f2bf(f.z); o.w = f2bf(f.w);
        *(s16x4*)&xb[i * 1024 + ((tid * 4) ^ ((i & 7) << 3))] = o;
    }
    __syncthreads();

    f32x4 acc[4];
    for (int i = 0; i < 4; ++i) acc[i] = (f32x4)0.0f;

    const int arow = wr * 16 + l15;
    const int aswz = (arow & 7) << 3;
    const short* arowp = &xb[arow * 1024];

    const short* wcol[4];
    for (int nt = 0; nt < 4; ++nt)
        wcol[nt] = wsrc + (size_t)(wc * 64 + nt * 16 + l15) * DIMX + quad * 8;

    bf16x8 bA[4], bB[4];
    for (int nt = 0; nt < 4; ++nt) bA[nt] = *(const bf16x8*)(wcol[nt]);

    for (int kk = 0; kk < 32; kk += 2) {
        for (int nt = 0; nt < 4; ++nt)
            bB[nt] = *(const bf16x8*)(wcol[nt] + (kk + 1) * 32);
        const bf16x8 a0 = *(const bf16x8*)&arowp[(kk * 32 + quad * 8) ^ aswz];
        for (int nt = 0; nt < 4; ++nt)
            acc[nt] = __builtin_amdgcn_mfma_f32_16x16x32_bf16(a0, bA[nt], acc[nt], 0, 0, 0);
        if (kk + 2 < 32)
            for (int nt = 0; nt < 4; ++nt)
                bA[nt] = *(const bf16x8*)(wcol[nt] + (kk + 2) * 32);
        const bf16x8 a1 = *(const bf16x8*)&arowp[((kk + 1) * 32 + quad * 8) ^ aswz];
        for (int nt = 0; nt < 4; ++nt)
            acc[nt] = __builtin_amdgcn_mfma_f32_16x16x32_bf16(a1, bB[nt], acc[nt], 0, 0, 0);
    }

    const int rw = rbase + wr * 16 + quad * 4;
    for (int nt = 0; nt < 4; ++nt) {
        const int col = wc * 64 + nt * 16 + l15;
        const float bias = bb[mat * DKV + col];
        if (mat == 0) {
            for (int r = 0; r < 4; ++r)
                qkb[(size_t)(rw + r) * DKV + col] = f2bf(acc[nt][r] + bias);
        } else {
            s16x4 o;
            o.x = f2bf(acc[nt][0] + bias); o.y = f2bf(acc[nt][1] + bias);
            o.z = f2bf(acc[nt][2] + bias); o.w = f2bf(acc[nt][3] + bias);
            *(s16x4*)&vtb[(size_t)col * NROWS + rw] = o;
        }
    }
}

// ---------------------------------------------------------------------------
// flash v8 = r8 skeleton (verified 55.8us: DMA K staging, dbuf, one barrier
// per tile, interleaved-key QK^T, b32 P path, lsum-via-MFMA) with ONE change:
// V is no longer staged in LDS. V-fragments load per-lane from L2 into a
// register ping-pong (vfA/vfB), ISSUED AT THE TOP OF TILE t FOR TILE t+1 --
// the end-of-tile barrier's vmcnt(0) drain guarantees arrival, with a full
// tile of compute as shadow (the r9 failure was prefetch distance, not the
// direct loads). Removes 8 of 18 LDS b128 reads/wave/tile + half the DMA.
// LDS 80 -> 48 KB. Loop 2x-unrolled so all buffer indices are static.
// ---------------------------------------------------------------------------
__global__ __launch_bounds__(256, 2) void flash_kernel(
    const short* __restrict__ qkb, const short* __restrict__ vtb,
    float* __restrict__ opart, float* __restrict__ lpart)
{
    __shared__ __align__(16) short kt[2][64 * 128];  // 32 KB, swizzled (DMA dest)
    __shared__ __align__(16) short pb[4][32 * 64];   // 16 KB, per-wave P (b32 path)
    // epilogue reuses kt (32 KB) as the rg merge buffer, pb head as l buffer

    const int tid  = threadIdx.x;
    const int lane = tid & 63;
    const int wave = tid >> 6;
    const int l15  = lane & 15;
    const int quad = lane >> 4;
    const int rg   = wave >> 1;                      // row-group (32 rows)
    const int kh   = wave & 1;                       // key-half (32 keys)
    const int rbase = blockIdx.x * 64 + rg * 32;
    const int ks = blockIdx.y;

    // K DMA source offsets (inverse-swizzled, r8-verified)
    unsigned koff[4];
    for (int i = 0; i < 4; ++i) {
        const int krow = wave * 16 + i * 4 + quad;
        koff[i] = (unsigned)krow * 256u
                + (((unsigned)l15 * 16u) ^ (((unsigned)krow & 7u) << 4));
    }

#define FL_ISSUE(buf, j0) do { \
        const char* kb_ = (const char*)qkb + (size_t)(j0) * (DKV * 2); \
        for (int i = 0; i < 4; ++i) \
            __builtin_amdgcn_global_load_lds( \
                (const __attribute__((address_space(1))) void*)(kb_ + koff[i]), \
                (__attribute__((address_space(3))) void*)((char*)&kt[buf][0] + (wave * 4 + i) * 1024), \
                16, 0, 0); \
    } while (0)

    // V direct-load base: row d = nt*16+l15 of vtb, key col kh*32 + quad*8
    const short* vpb = vtb + (size_t)l15 * NROWS + kh * 32 + quad * 8;
#define LOADV(dst, j0) do { \
        for (int nt_ = 0; nt_ < 8; ++nt_) \
            dst[nt_] = *(const bf16x8*)(vpb + (size_t)nt_ * (16 * NROWS) + (j0)); \
    } while (0)

    // Q fragments for 32 rows: A[m=lane&15][k=quad*8+j], halves h=0,1
    bf16x8 qf[2][4];
    #pragma unroll 2
    for (int h = 0; h < 2; ++h) {
        const short* qrow = qkb + (size_t)(rbase + h * 16 + l15) * DKV;
        for (int k = 0; k < 4; ++k)
            qf[h][k] = *(const bf16x8*)(qrow + k * 32 + quad * 8);
    }

    // ones-vector (bf16 1.0) for the l-sum MFMA
    bf16x8 ones;
    for (int j = 0; j < 8; ++j) ones[j] = (short)0x3F80;

    f32x4 oacc[2][8];
    #pragma unroll 2
    for (int h = 0; h < 2; ++h)
        for (int i = 0; i < 8; ++i) oacc[h][i] = (f32x4)0.0f;
    f32x4 lsum[2] = {(f32x4)0.0f, (f32x4)0.0f};

    short* pw = &pb[wave][0];                        // 32 rows x 128 B

    // QK^T B rows (interleaved keys): row0 = kh*32 + 2*l15 (+ntl)
    const int krow0 = kh * 32 + 2 * l15;
    const int swk0  = ((krow0 & 7) << 3);            // shorts; row0 even
    // P-store/load XOR (bytes): X(row) = ((row>>2)&1)<<6 (r8-verified)
    const int pxw = (quad & 1) << 6;                 // write: row=h*16+quad*4+r
    const int pxr = (l15 & 4) << 4;                  // read:  row=h*16+l15

#define TILE(CUR, NXT, VC, VN, j0, more) do { \
        if (more) { FL_ISSUE(NXT, (j0) + BN); LOADV(VN, (j0) + BN); } \
        f32x4 s[2][2]; \
        __builtin_amdgcn_s_setprio(1); \
        for (int ntl = 0; ntl < 2; ++ntl) { \
            f32x4 a0 = (f32x4)0.0f, a1 = (f32x4)0.0f; \
            const int rowb = (krow0 + ntl) * 128; \
            const int swk  = swk0 + ntl * 8; \
            for (int k_ = 0; k_ < 4; ++k_) { \
                const bf16x8 b = *(const bf16x8*) \
                    &kt[CUR][rowb + ((k_ * 32 + quad * 8) ^ swk)]; \
                a0 = __builtin_amdgcn_mfma_f32_16x16x32_bf16(qf[0][k_], b, a0, 0, 0, 0); \
                a1 = __builtin_amdgcn_mfma_f32_16x16x32_bf16(qf[1][k_], b, a1, 0, 0, 0); \
            } \
            s[0][ntl] = a0; s[1][ntl] = a1; \
        } \
        __builtin_amdgcn_s_setprio(0); \
        for (int h = 0; h < 2; ++h) \
            for (int ntl = 0; ntl < 2; ++ntl) \
                for (int r = 0; r < 4; ++r) \
                    s[h][ntl][r] = __builtin_amdgcn_exp2f(s[h][ntl][r] - M_FIX); \
        for (int h = 0; h < 2; ++h) \
            for (int r = 0; r < 4; ++r) { \
                const int row = h * 16 + quad * 4 + r; \
                unsigned pk; \
                asm("v_cvt_pk_bf16_f32 %0, %1, %2" : "=v"(pk) : "v"(s[h][0][r]), "v"(s[h][1][r])); \
                *(unsigned*)((char*)pw + row * 128 + ((l15 * 4) ^ pxw)) = pk; \
            } \
        __builtin_amdgcn_s_setprio(1); \
        { \
            const bf16x8 a0 = *(const bf16x8*)((char*)pw + l15 * 128 + ((quad * 16) ^ pxr)); \
            const bf16x8 a1 = *(const bf16x8*)((char*)pw + (16 + l15) * 128 + ((quad * 16) ^ pxr)); \
            lsum[0] = __builtin_amdgcn_mfma_f32_16x16x32_bf16(a0, ones, lsum[0], 0, 0, 0); \
            lsum[1] = __builtin_amdgcn_mfma_f32_16x16x32_bf16(a1, ones, lsum[1], 0, 0, 0); \
            for (int nt_ = 0; nt_ < 8; ++nt_) { \
                oacc[0][nt_] = __builtin_amdgcn_mfma_f32_16x16x32_bf16(a0, VC[nt_], oacc[0][nt_], 0, 0, 0); \
                oacc[1][nt_] = __builtin_amdgcn_mfma_f32_16x16x32_bf16(a1, VC[nt_], oacc[1][nt_], 0, 0, 0); \
            } \
        } \
        __builtin_amdgcn_s_setprio(0); \
        __syncthreads();   /* drains vmcnt: next K tile + VN regs landed */ \
    } while (0)

    const int j_begin = ks * KEYS_PER_SPLIT;
    const int j_end   = j_begin + KEYS_PER_SPLIT;

    bf16x8 vfA[8], vfB[8];
    FL_ISSUE(0, j_begin);
    LOADV(vfA, j_begin);
    __syncthreads();                                 // buf0 + vfA ready

    for (int j0 = j_begin; j0 < j_end; j0 += 2 * BN) {
        TILE(0, 1, vfA, vfB, j0, true);
        TILE(1, 0, vfB, vfA, j0 + BN, (j0 + 2 * BN) < j_end);
    }

    // ---- merge the two key-half waves of each row-group (plain adds) ----
    // loop-trailing barrier already separates last kt reads from obuf writes
    float* obuf = (float*)&kt[0][0] + rg * 32 * 128; // 32 rows x 128 d fp32
    float* lbuf = (float*)&pb[0][0];                 // 64 floats
    if (kh == 1) {
        #pragma unroll 2
        for (int h = 0; h < 2; ++h) {
            for (int nt = 0; nt < 8; ++nt)
                for (int r = 0; r < 4; ++r)
                    obuf[(h * 16 + quad * 4 + r) * 128 + nt * 16 + l15] = oacc[h][nt][r];
            if (l15 == 0)
                for (int r = 0; r < 4; ++r)
                    lbuf[rg * 32 + h * 16 + quad * 4 + r] = lsum[h][r];
        }
    }
    __syncthreads();
    if (kh == 0) {
        #pragma unroll 2
        for (int h = 0; h < 2; ++h) {
            const int rw = rbase + h * 16 + quad * 4;
            for (int nt = 0; nt < 8; ++nt) {
                const int col = nt * 16 + l15;
                for (int r = 0; r < 4; ++r)
                    opart[((size_t)ks * NROWS + rw + r) * DKV + col] =
                        oacc[h][nt][r] + obuf[(h * 16 + quad * 4 + r) * 128 + col];
            }
            if (l15 == 0)
                for (int r = 0; r < 4; ++r)
                    lpart[ks * NROWS + rw + r] =
                        lsum[h][r] + lbuf[rg * 32 + h * 16 + quad * 4 + r];
        }
    }
#undef FL_ISSUE
#undef LOADV
#undef TILE
}

// ---------------------------------------------------------------------------
// combine: fixed common max -> plain sums, one divide
// ---------------------------------------------------------------------------
__global__ __launch_bounds__(256) void combine_kernel(
    const float* __restrict__ opart, const float* __restrict__ lpart,
    float* __restrict__ out)
{
    const int idx = blockIdx.x * 256 + threadIdx.x;  // 0 .. N*128-1
    const int row = idx >> 7;
    float L = 0.f, acc = 0.f;
    for (int s = 0; s < KSPLIT; ++s) {
        L   += lpart[s * NROWS + row];
        acc += opart[(size_t)s * NROWS * DKV + idx];
    }
    out[idx] = acc / L;
}

// ---------------------------------------------------------------------------
extern "C" void kernel_launch(void* const* d_in, const int* in_sizes, int n_in,
                              void* d_out, int out_size, void* d_ws, size_t ws_size,
                              hipStream_t stream) {
    const float* x   = (const float*)d_in[0];
    const float* Wqk = (const float*)d_in[1];
    const float* bqk = (const float*)d_in[2];
    const float* Wv  = (const float*)d_in[3];
    const float* bv  = (const float*)d_in[4];
    float* out = (float*)d_out;

    char* ws = (char*)d_ws;
    short* qkb   = (short*)ws;                                   // 2 MB bf16 [N][128]
    short* vtb   = (short*)(ws + (2u << 20));                    // 2 MB bf16 [128][N]
    short* wb    = (short*)(ws + (4u << 20));                    // 512 KB bf16 [2][128][1024]
    float* bb    = (float*)(ws + (4u << 20) + (512u << 10));     // 1 KB fp32 [256]
    float* opart = (float*)(ws + (5u << 20));                    // 16 MB fp32 [KS][N][128]
    float* lpart = (float*)(ws + (21u << 20));                   // 128 KB

    wcvt_kernel<<<dim3(256), 256, 0, stream>>>(Wqk, bqk, Wv, bv, wb, bb);
    proj_kernel<<<dim3(256, 2), 256, 0, stream>>>(x, wb, bb, qkb, vtb);
    flash_kernel<<<dim3(NROWS / 64, KSPLIT), 256, 0, stream>>>(qkb, vtb, opart, lpart);
    combine_kernel<<<dim3(NROWS * DKV / 256), 256, 0, stream>>>(opart, lpart, out);
}

// Round 11
// 156.194 us; speedup vs baseline: 1.5015x; 1.2226x over previous
//
#include <hip/hip_runtime.h>
#include <math.h>

#define NROWS 8192
#define DIMX  1024
#define DKV   128
#define KSPLIT 4
#define KEYS_PER_SPLIT (NROWS / KSPLIT)  // 2048
#define BN 64
// sqrt(log2(e)) -- folded into Wqk/bqk so scores come out in base-2 units
#define QK_SCALE 1.2011224087864498f
// fixed softmax max (base-2 units); see round-6 derivation
#define M_FIX 96.0f

typedef __attribute__((ext_vector_type(8))) short bf16x8;
typedef __attribute__((ext_vector_type(4))) short s16x4;
typedef __attribute__((ext_vector_type(4))) float f32x4;
typedef __attribute__((ext_vector_type(4))) unsigned u32x4;

static __device__ __forceinline__ short f2bf(float f) {
    union { float f; unsigned u; } v; v.f = f;
    unsigned r = v.u + 0x7fff + ((v.u >> 16) & 1);  // RNE
    return (short)(r >> 16);
}

// ---------------------------------------------------------------------------
// wcvt: one-time W/bias convert to bf16 (Wqk,bqk pre-scaled by sqrt(log2 e)).
// ---------------------------------------------------------------------------
__global__ __launch_bounds__(256) void wcvt_kernel(
    const float* __restrict__ Wqk, const float* __restrict__ bqk,
    const float* __restrict__ Wv,  const float* __restrict__ bv,
    short* __restrict__ wb, float* __restrict__ bb)
{
    const int idx = blockIdx.x * 1024 + threadIdx.x * 4;   // 256 blocks x 1024
    const bool isqk = idx < DKV * DIMX;
    const float* src = isqk ? (Wqk + idx) : (Wv + (idx - DKV * DIMX));
    const float sc = isqk ? QK_SCALE : 1.0f;
    const float4 f = *(const float4*)src;
    s16x4 o;
    o.x = f2bf(f.x * sc); o.y = f2bf(f.y * sc);
    o.z = f2bf(f.z * sc); o.w = f2bf(f.w * sc);
    *(s16x4*)&wb[idx] = o;
    if (blockIdx.x == 0) {
        const int t = threadIdx.x;
        bb[t] = (t < DKV) ? bqk[t] * QK_SCALE : bv[t - DKV];
    }
}

// ---------------------------------------------------------------------------
// proj v3: stage-once + software-pipelined B loads (unchanged from r10).
// ---------------------------------------------------------------------------
__global__ __launch_bounds__(256) void proj_kernel(
    const float* __restrict__ x, const short* __restrict__ wb,
    const float* __restrict__ bb, short* __restrict__ qkb, short* __restrict__ vtb)
{
    __shared__ __align__(16) short xb[32 * 1024];  // 64 KB, XOR-swizzled

    const int tid  = threadIdx.x;
    const int lane = tid & 63;
    const int wave = tid >> 6;
    const int l15  = lane & 15;
    const int quad = lane >> 4;
    const int mat  = blockIdx.y;
    const int rbase = blockIdx.x * 32;
    const int wr = wave >> 1, wc = wave & 1;       // wave: 16 rows x 64 cols
    const short* wsrc = wb + (size_t)mat * DKV * DIMX;

    #pragma unroll 8
    for (int i = 0; i < 32; ++i) {
        const float4 f = *(const float4*)(x + (size_t)(rbase + i) * DIMX + tid * 4);
        s16x4 o;
        o.x = f2bf(f.x); o.y = f2bf(f.y); o.z = f2bf(f.z); o.w = f2bf(f.w);
        *(s16x4*)&xb[i * 1024 + ((tid * 4) ^ ((i & 7) << 3))] = o;
    }
    __syncthreads();

    f32x4 acc[4];
    for (int i = 0; i < 4; ++i) acc[i] = (f32x4)0.0f;

    const int arow = wr * 16 + l15;
    const int aswz = (arow & 7) << 3;
    const short* arowp = &xb[arow * 1024];

    const short* wcol[4];
    for (int nt = 0; nt < 4; ++nt)
        wcol[nt] = wsrc + (size_t)(wc * 64 + nt * 16 + l15) * DIMX + quad * 8;

    bf16x8 bA[4], bB[4];
    for (int nt = 0; nt < 4; ++nt) bA[nt] = *(const bf16x8*)(wcol[nt]);

    for (int kk = 0; kk < 32; kk += 2) {
        for (int nt = 0; nt < 4; ++nt)
            bB[nt] = *(const bf16x8*)(wcol[nt] + (kk + 1) * 32);
        const bf16x8 a0 = *(const bf16x8*)&arowp[(kk * 32 + quad * 8) ^ aswz];
        for (int nt = 0; nt < 4; ++nt)
            acc[nt] = __builtin_amdgcn_mfma_f32_16x16x32_bf16(a0, bA[nt], acc[nt], 0, 0, 0);
        if (kk + 2 < 32)
            for (int nt = 0; nt < 4; ++nt)
                bA[nt] = *(const bf16x8*)(wcol[nt] + (kk + 2) * 32);
        const bf16x8 a1 = *(const bf16x8*)&arowp[((kk + 1) * 32 + quad * 8) ^ aswz];
        for (int nt = 0; nt < 4; ++nt)
            acc[nt] = __builtin_amdgcn_mfma_f32_16x16x32_bf16(a1, bB[nt], acc[nt], 0, 0, 0);
    }

    const int rw = rbase + wr * 16 + quad * 4;
    for (int nt = 0; nt < 4; ++nt) {
        const int col = wc * 64 + nt * 16 + l15;
        const float bias = bb[mat * DKV + col];
        if (mat == 0) {
            for (int r = 0; r < 4; ++r)
                qkb[(size_t)(rw + r) * DKV + col] = f2bf(acc[nt][r] + bias);
        } else {
            s16x4 o;
            o.x = f2bf(acc[nt][0] + bias); o.y = f2bf(acc[nt][1] + bias);
            o.z = f2bf(acc[nt][2] + bias); o.w = f2bf(acc[nt][3] + bias);
            *(s16x4*)&vtb[(size_t)col * NROWS + rw] = o;
        }
    }
}

// ---------------------------------------------------------------------------
// flash v9 = r8 skeleton (DMA K+V staging, dbuf, 1 barrier/tile; verified
// 55.8us) + ZERO-LDS P via swapped QK^T (T12):
//  - compute mfma(K, Q) so C[m=key][n=q]: lane l15 = q, regs = keys -> after
//    exp2 each lane holds P[q=l15][8 keys] = EXACTLY the PV A-fragment.
//  - K-DMA source rows permuted (sigma: s -> 4*(s&1)+(s>>1) within 8-row
//    groups) so stored-row reads (unchanged 2*l15+ntl pattern, byte-identical
//    LDS access) yield keys 8g+4*ntl+r = natural V order. Verified by trace.
//  - P: exp2 -> 8 cvt_pk -> MFMA operands. No ds_write/ds_read, no pb LDS
//    (80->64 KB), no softmax->PV lgkm serialization.
// Q becomes the B operand (same fragment formula); lsum/PV/merge layouts
// land identically to r8 (C layout col=lane&15, row=quad*4+reg).
// ---------------------------------------------------------------------------
__global__ __launch_bounds__(256, 2) void flash_kernel(
    const short* __restrict__ qkb, const short* __restrict__ vtb,
    float* __restrict__ opart, float* __restrict__ lpart)
{
    __shared__ __align__(16) short kt[2][64 * 128];  // 32 KB, swizzled (DMA dest)
    __shared__ __align__(16) short vt[2][128 * 64];  // 32 KB, swizzled (DMA dest)
    // epilogue reuses kt (32 KB) as the rg merge buffer, vt head as l buffer

    const int tid  = threadIdx.x;
    const int lane = tid & 63;
    const int wave = tid >> 6;
    const int l15  = lane & 15;
    const int quad = lane >> 4;
    const int rg   = wave >> 1;                      // row-group (32 rows)
    const int kh   = wave & 1;                       // key-half (32 keys)
    const int rbase = blockIdx.x * 64 + rg * 32;
    const int ks = blockIdx.y;
    const int swzr = (l15 & 7) << 3;                 // vt read XOR (shorts)

    // DMA source offsets (inverse-swizzled). K rows permuted by sigma so the
    // swapped-QK^T output keys match V's natural order.
    unsigned koff[4], voff[4];
    for (int i = 0; i < 4; ++i) {
        const int krow = wave * 16 + i * 4 + quad;   // stored kt row
        const int s = krow & 7;
        const int srow = (krow & ~7) | (((s & 1) << 2) | (s >> 1));  // key row
        koff[i] = (unsigned)srow * 256u
                + (((unsigned)l15 * 16u) ^ (((unsigned)krow & 7u) << 4));
        const int vrow = wave * 32 + i * 8 + (lane >> 3);
        voff[i] = (unsigned)vrow * (unsigned)(NROWS * 2)
                + ((((unsigned)lane & 7u) * 16u) ^ (((unsigned)vrow & 7u) << 4));
    }

#define FL_ISSUE(buf, j0) do { \
        const char* kb_ = (const char*)qkb + (size_t)(j0) * (DKV * 2); \
        const char* vb_ = (const char*)vtb + (size_t)(j0) * 2; \
        for (int i = 0; i < 4; ++i) \
            __builtin_amdgcn_global_load_lds( \
                (const __attribute__((address_space(1))) void*)(kb_ + koff[i]), \
                (__attribute__((address_space(3))) void*)((char*)&kt[buf][0] + (wave * 4 + i) * 1024), \
                16, 0, 0); \
        for (int i = 0; i < 4; ++i) \
            __builtin_amdgcn_global_load_lds( \
                (const __attribute__((address_space(1))) void*)(vb_ + voff[i]), \
                (__attribute__((address_space(3))) void*)((char*)&vt[buf][0] + (wave * 4 + i) * 1024), \
                16, 0, 0); \
    } while (0)

    // Q fragments for 32 rows (now the B operand; same fragment formula)
    bf16x8 qf[2][4];
    #pragma unroll 2
    for (int h = 0; h < 2; ++h) {
        const short* qrow = qkb + (size_t)(rbase + h * 16 + l15) * DKV;
        for (int k = 0; k < 4; ++k)
            qf[h][k] = *(const bf16x8*)(qrow + k * 32 + quad * 8);
    }

    // ones-vector (bf16 1.0) for the l-sum MFMA
    bf16x8 ones;
    for (int j = 0; j < 8; ++j) ones[j] = (short)0x3F80;

    f32x4 oacc[2][8];
    #pragma unroll 2
    for (int h = 0; h < 2; ++h)
        for (int i = 0; i < 8; ++i) oacc[h][i] = (f32x4)0.0f;
    f32x4 lsum[2] = {(f32x4)0.0f, (f32x4)0.0f};

    // QK^T A-operand (K) stored-row base: kh*32 + 2*l15 (+ntl); XOR as r8
    const int krow0 = kh * 32 + 2 * l15;
    const int swk0  = ((krow0 & 7) << 3);            // shorts; krow0 even

#define TILE(CUR, NXT, j0, more) do { \
        if (more) FL_ISSUE(NXT, (j0) + BN); \
        f32x4 s[2][2]; \
        __builtin_amdgcn_s_setprio(1); \
        for (int ntl = 0; ntl < 2; ++ntl) { \
            f32x4 a0 = (f32x4)0.0f, a1 = (f32x4)0.0f; \
            const int rowb = (krow0 + ntl) * 128; \
            const int swk  = swk0 + ntl * 8; \
            for (int k_ = 0; k_ < 4; ++k_) { \
                const bf16x8 kb = *(const bf16x8*) \
                    &kt[CUR][rowb + ((k_ * 32 + quad * 8) ^ swk)]; \
                a0 = __builtin_amdgcn_mfma_f32_16x16x32_bf16(kb, qf[0][k_], a0, 0, 0, 0); \
                a1 = __builtin_amdgcn_mfma_f32_16x16x32_bf16(kb, qf[1][k_], a1, 0, 0, 0); \
            } \
            s[0][ntl] = a0; s[1][ntl] = a1; \
        } \
        __builtin_amdgcn_s_setprio(0); \
        for (int h = 0; h < 2; ++h) \
            for (int ntl = 0; ntl < 2; ++ntl) \
                for (int r = 0; r < 4; ++r) \
                    s[h][ntl][r] = __builtin_amdgcn_exp2f(s[h][ntl][r] - M_FIX); \
        bf16x8 pa[2]; \
        for (int h = 0; h < 2; ++h) { \
            u32x4 t; \
            asm("v_cvt_pk_bf16_f32 %0, %1, %2" : "=v"(t.x) : "v"(s[h][0][0]), "v"(s[h][0][1])); \
            asm("v_cvt_pk_bf16_f32 %0, %1, %2" : "=v"(t.y) : "v"(s[h][0][2]), "v"(s[h][0][3])); \
            asm("v_cvt_pk_bf16_f32 %0, %1, %2" : "=v"(t.z) : "v"(s[h][1][0]), "v"(s[h][1][1])); \
            asm("v_cvt_pk_bf16_f32 %0, %1, %2" : "=v"(t.w) : "v"(s[h][1][2]), "v"(s[h][1][3])); \
            pa[h] = *(bf16x8*)&t; \
        } \
        __builtin_amdgcn_s_setprio(1); \
        lsum[0] = __builtin_amdgcn_mfma_f32_16x16x32_bf16(pa[0], ones, lsum[0], 0, 0, 0); \
        lsum[1] = __builtin_amdgcn_mfma_f32_16x16x32_bf16(pa[1], ones, lsum[1], 0, 0, 0); \
        for (int nt_ = 0; nt_ < 8; ++nt_) { \
            const bf16x8 vb = *(const bf16x8*) \
                &vt[CUR][(nt_ * 16 + l15) * 64 + ((kh * 32 + quad * 8) ^ swzr)]; \
            oacc[0][nt_] = __builtin_amdgcn_mfma_f32_16x16x32_bf16(pa[0], vb, oacc[0][nt_], 0, 0, 0); \
            oacc[1][nt_] = __builtin_amdgcn_mfma_f32_16x16x32_bf16(pa[1], vb, oacc[1][nt_], 0, 0, 0); \
        } \
        __builtin_amdgcn_s_setprio(0); \
        __syncthreads();   /* drains vmcnt: next tile's DMA landed */ \
    } while (0)

    const int j_begin = ks * KEYS_PER_SPLIT;
    const int j_end   = j_begin + KEYS_PER_SPLIT;

    FL_ISSUE(0, j_begin);
    __syncthreads();                                 // buf0 ready

    for (int j0 = j_begin; j0 < j_end; j0 += 2 * BN) {
        TILE(0, 1, j0, true);
        TILE(1, 0, j0 + BN, (j0 + 2 * BN) < j_end);
    }

    // ---- merge the two key-half waves of each row-group (plain adds) ----
    // loop-trailing barrier separates last kt/vt reads from buffer reuse
    float* obuf = (float*)&kt[0][0] + rg * 32 * 128; // 32 rows x 128 d fp32
    float* lbuf = (float*)&vt[0][0];                 // 64 floats
    if (kh == 1) {
        #pragma unroll 2
        for (int h = 0; h < 2; ++h) {
            for (int nt = 0; nt < 8; ++nt)
                for (int r = 0; r < 4; ++r)
                    obuf[(h * 16 + quad * 4 + r) * 128 + nt * 16 + l15] = oacc[h][nt][r];
            if (l15 == 0)
                for (int r = 0; r < 4; ++r)
                    lbuf[rg * 32 + h * 16 + quad * 4 + r] = lsum[h][r];
        }
    }
    __syncthreads();
    if (kh == 0) {
        #pragma unroll 2
        for (int h = 0; h < 2; ++h) {
            const int rw = rbase + h * 16 + quad * 4;
            for (int nt = 0; nt < 8; ++nt) {
                const int col = nt * 16 + l15;
                for (int r = 0; r < 4; ++r)
                    opart[((size_t)ks * NROWS + rw + r) * DKV + col] =
                        oacc[h][nt][r] + obuf[(h * 16 + quad * 4 + r) * 128 + col];
            }
            if (l15 == 0)
                for (int r = 0; r < 4; ++r)
                    lpart[ks * NROWS + rw + r] =
                        lsum[h][r] + lbuf[rg * 32 + h * 16 + quad * 4 + r];
        }
    }
#undef FL_ISSUE
#undef TILE
}

// ---------------------------------------------------------------------------
// combine: fixed common max -> plain sums, one divide
// ---------------------------------------------------------------------------
__global__ __launch_bounds__(256) void combine_kernel(
    const float* __restrict__ opart, const float* __restrict__ lpart,
    float* __restrict__ out)
{
    const int idx = blockIdx.x * 256 + threadIdx.x;  // 0 .. N*128-1
    const int row = idx >> 7;
    float L = 0.f, acc = 0.f;
    for (int s = 0; s < KSPLIT; ++s) {
        L   += lpart[s * NROWS + row];
        acc += opart[(size_t)s * NROWS * DKV + idx];
    }
    out[idx] = acc / L;
}

// ---------------------------------------------------------------------------
extern "C" void kernel_launch(void* const* d_in, const int* in_sizes, int n_in,
                              void* d_out, int out_size, void* d_ws, size_t ws_size,
                              hipStream_t stream) {
    const float* x   = (const float*)d_in[0];
    const float* Wqk = (const float*)d_in[1];
    const float* bqk = (const float*)d_in[2];
    const float* Wv  = (const float*)d_in[3];
    const float* bv  = (const float*)d_in[4];
    float* out = (float*)d_out;

    char* ws = (char*)d_ws;
    short* qkb   = (short*)ws;                                   // 2 MB bf16 [N][128]
    short* vtb   = (short*)(ws + (2u << 20));                    // 2 MB bf16 [128][N]
    short* wb    = (short*)(ws + (4u << 20));                    // 512 KB bf16 [2][128][1024]
    float* bb    = (float*)(ws + (4u << 20) + (512u << 10));     // 1 KB fp32 [256]
    float* opart = (float*)(ws + (5u << 20));                    // 16 MB fp32 [KS][N][128]
    float* lpart = (float*)(ws + (21u << 20));                   // 128 KB

    wcvt_kernel<<<dim3(256), 256, 0, stream>>>(Wqk, bqk, Wv, bv, wb, bb);
    proj_kernel<<<dim3(256, 2), 256, 0, stream>>>(x, wb, bb, qkb, vtb);
    flash_kernel<<<dim3(NROWS / 64, KSPLIT), 256, 0, stream>>>(qkb, vtb, opart, lpart);
    combine_kernel<<<dim3(NROWS * DKV / 256), 256, 0, stream>>>(opart, lpart, out);
}